// Round 8
// baseline (141.212 us; speedup 1.0000x reference)
//
#include <hip/hip_runtime.h>
#include <hip/hip_bf16.h>
#include <stdint.h>

// Conv2d: x[128][256][256] (f32), w[256][128][3][3] (f32), bias[256] (f32)
// out[256][256][256] (f32).  pad=1, stride=1.
// bf16 MFMA implicit GEMM: M=COUT=256, N=65536 pixels, K=9 taps x 128 ch = 1152.
//   ws: x_p bf16 [258][258][128] (padded, channel-innermost),
//       apk bf16 fragment-packed weights [9][2][2][16][64][8].
//
// R10 (post-mortem R9: pipes fully serialized -- per-tile 4530 cyc ~= VMEM 1024
// + LDSwr 512 + LDSrd 1536 + MFMA 1242 summed. global_load_lds writes queue
// behind the ds_read flood on the SAME LDS port -> stage drains at the barrier;
// co-resident blocks convoy on shared ports. Fix = remove bytes from LDS):
//   - A NEVER touches LDS. prep packs weights in MFMA-fragment order
//     apk[kk][hf][ks][mb][lane][8]; an a-frag = one coalesced 1KB
//     global_load_dwordx4 (L2-resident 0.6MB). Deletes 32KB A-writes +
//     64KB A-reads per tile/CU: LDS traffic -50%.
//   - Block 128x256, 8 waves of 64x64, grid 512 = exactly 2 blocks/CU.
//     LDS = B-only dbuf 2x32KB = 64KB.
//   - Per tile: [s_barrier][a-ks0 x4 ->reg][stage(t+1) x4 gload_lds]
//     [b-ks0 ds_read + 16 MFMA][a-ks1 x4][b-ks1 + 16 MFMA].
//     FIFO order makes the compiler's own vmcnt before a-ks1's use retire the
//     stage mid-tile (~1000 cyc slack) -> top-of-tile barrier is wait-free;
//     no manual vmcnt asm (no rule-18 hazard).
//   - B keeps the proven swizzle triple (linear gload_lds dest + pre-swizzled
//     source + XOR-swizzled ds_read; 0 conflicts in R6/R7/R9).
// FP accumulation order identical to R9 -> bit-identical output expected.

#define CIN   128
#define COUT  256
#define HH    256
#define WW    256
#define HP    258
#define WP    258
#define XP_ELEMS (HP * WP * CIN)   // 8,520,192 bf16 elements

typedef __attribute__((ext_vector_type(8))) __bf16 bf16x8;
typedef __attribute__((ext_vector_type(4))) float  floatx4;
typedef __attribute__((ext_vector_type(8))) short  short8;

#define AS1 __attribute__((address_space(1)))
#define AS3 __attribute__((address_space(3)))

// ---------------- fused prep: xpose_pad | a-frag pack | zero_border ----------------
__global__ __launch_bounds__(256) void prep(const float* __restrict__ x,
                                            const float* __restrict__ w,
                                            unsigned short* __restrict__ xp,
                                            unsigned short* __restrict__ apk) {
    __shared__ __align__(16) unsigned short tile[64][136];  // xpose region only
    const int bid = blockIdx.x;
    const int t   = threadIdx.x;
    if (bid < 1024) {
        // transpose+cast x[c][h][w] -> x_p[h+1][w+1][c]
        int h  = bid >> 2;
        int w0 = (bid & 3) << 6;
        int wl = t & 63, icq = t >> 6;
        const float* src = x + h * WW + w0 + wl;
#pragma unroll
        for (int icb = 0; icb < 32; ++icb) {
            int ic = icb * 4 + icq;
            __hip_bfloat16 b = __float2bfloat16(src[ic * (HH * WW)]);
            tile[wl][ic] = __builtin_bit_cast(unsigned short, b);
        }
        __syncthreads();
        int wl2 = t >> 2, q = t & 3;    // 64 rows x 4 chunks of 64B
        const short8* s8 = (const short8*)&tile[wl2][q * 32];
        short8* d8 = (short8*)(xp + ((size_t)(h + 1) * WP + (w0 + 1) + wl2) * CIN + q * 32);
#pragma unroll
        for (int i = 0; i < 4; ++i) d8[i] = s8[i];
    } else if (bid < 2176) {
        // pack weights into MFMA-fragment order:
        // apk[kk][hf][ks][mb][l][j] = w[o=mb*16+(l&15)][ch=hf*64+ks*32+(l>>4)*8+j][kk]
        int idx = (bid - 1024) * 256 + t;           // 0..294911
        int j  = idx & 7;
        int l  = (idx >> 3) & 63;
        int mb = (idx >> 9) & 15;
        int ks = (idx >> 13) & 1;
        int hf = (idx >> 14) & 1;
        int kk = idx >> 15;
        int o  = mb * 16 + (l & 15);
        int ch = hf * 64 + ks * 32 + (l >> 4) * 8 + j;
        __hip_bfloat16 b = __float2bfloat16(w[(o * CIN + ch) * 9 + kk]);
        apk[idx] = __builtin_bit_cast(unsigned short, b);
    } else {
        // zero the padded border: 1028 px x 16 octets, short8 stores
        int cid = (bid - 2176) * 256 + t;           // 0..16447
        if (cid < 16448) {
            int p = cid >> 4, oct = cid & 15;
            int hp, wp;
            if (p < 258)      { hp = 0;   wp = p; }
            else if (p < 516) { hp = 257; wp = p - 258; }
            else { int s = p - 516; hp = 1 + (s >> 1); wp = (s & 1) * 257; }
            short8 z = {0, 0, 0, 0, 0, 0, 0, 0};
            *(short8*)(xp + ((size_t)hp * WP + wp) * CIN + oct * 8) = z;
        }
    }
}

// ---------------- main: 128(M) x 256(pixels of row h), 8 waves, 18 K-tiles, 2 blocks/CU ----------------
// LDS per buffer (16384 shorts = 32KB): B[256 px][64 ch], granule XOR swizzle
// (physical granule = logical ^ (px & 7), granule = 8 shorts = 16B).
// A-fragments: direct global loads from apk, frag index f = ((kk*2+hf)*2+ks)*16+mb,
// address = apk + f*512 + lane*8  (1KB contiguous per fragment).
__global__ __launch_bounds__(512, 4) void conv_mfma(
    const unsigned short* __restrict__ xp,   // [258][258][128] bf16
    const unsigned short* __restrict__ apk,  // fragment-packed weights
    const float* __restrict__ bias,          // [256] f32
    float* __restrict__ out) {               // [256][65536] f32
    __shared__ __align__(16) unsigned short b_lds[2 * 16384];   // 65,536 B

    const int tid  = threadIdx.x;            // 0..511
    const int lane = tid & 63;
    const int wv   = tid >> 6;               // 0..7
    const int l15  = lane & 15;
    const int lg   = lane >> 4;              // 0..3
    const int wave_m = (wv >> 2) << 6;       // 0 or 64
    const int wave_n = (wv & 3) << 6;        // 0,64,128,192

    // XCD swizzle (bijective, 512 % 8 == 0): XCD k gets one m-half x 64-row band.
    const int orig = blockIdx.x;
    const int swz  = ((orig & 7) << 6) | (orig >> 3);
    const int m0 = (swz >> 8) << 7;          // 0 or 128
    const int h  = swz & 255;

    // B staging per-thread source offset: px = tid>>3, pre-swizzled granule.
    const int soff = (tid >> 3) * CIN + ((((tid & 7) ^ ((tid >> 3) & 7))) << 3);
    // a-frag block row base: mb0 = (m0 + wave_m)/16.
    const int mb0 = (m0 + wave_m) >> 4;

    // One B staging instr: 512 thr x 16B = 8KB = 64 px.
#define GLD_B(nb_, src_, i_) \
    __builtin_amdgcn_global_load_lds((const AS1 void*)((src_) + (i_) * 8192), \
        (AS3 void*)((nb_) + (i_) * 4096 + tid * 8), 16, 0, 0)

    // Swizzled B fragment read: px = wave_n + fj*16 + l15, logical granule ks*4+lg.
#define LDB(Bb_, fj_, ks_) \
    (*(const bf16x8*)((Bb_) + (((wave_n + (fj_) * 16) + l15) << 6) + \
                      ((((ks_) * 4 + lg) ^ (l15 & 7)) << 3)))
    // A fragment global load: frag (kk,hf,ks, mb0+fi).
#define LDA(f_) (*(const bf16x8*)(apk + (size_t)(f_) * 512 + lane * 8))

    auto stage = [&](int buf, int kh, int kw, int hf) {
        unsigned short* nb = b_lds + buf * 16384;
        const unsigned short* bsrc =
            xp + ((size_t)(h + kh) * WP + kw) * CIN + hf * 64 + soff;
#pragma unroll
        for (int i = 0; i < 4; ++i) GLD_B(nb, bsrc, i);
    };

    floatx4 acc[4][4];
#pragma unroll
    for (int fi = 0; fi < 4; ++fi)
#pragma unroll
        for (int fj = 0; fj < 4; ++fj) {
            floatx4 z = {0.f, 0.f, 0.f, 0.f};
            acc[fi][fj] = z;
        }

    // Prologue: stage tile 0 into buffer 0; full drain once.
    stage(0, 0, 0, 0);
    __syncthreads();

#pragma unroll
    for (int t2 = 0; t2 < 18; ++t2) {        // K-tile = (kk, ch-half)
        const int cur = t2 & 1;
        const unsigned short* Bb = b_lds + cur * 16384;
        const int kk = t2 >> 1, hf = t2 & 1;
        const int fb = ((kk * 2 + hf) * 2) * 16 + mb0;   // ks=0 frag base

        if (t2 > 0) __builtin_amdgcn_s_barrier();   // prev reads done; stage may begin

        // a-frags ks0 (oldest in vmcnt FIFO -> their wait leaves stage in flight)
        bf16x8 a0[4];
#pragma unroll
        for (int fi = 0; fi < 4; ++fi) a0[fi] = LDA(fb + fi);

        // issue next tile's B stage (4 gload_lds). Retired by the compiler's
        // own vmcnt wait before a-ks1 use (mid-tile, ~1000 cyc slack).
        if (t2 < 17) {
            const int tn  = t2 + 1;
            const int kkn = tn >> 1, hfn = tn & 1;
            const int khn = kkn / 3, kwn = kkn - khn * 3;
            stage(cur ^ 1, khn, kwn, hfn);
        }

        // ks0: B fragments + MFMA
        bf16x8 b0[4];
#pragma unroll
        for (int fj = 0; fj < 4; ++fj) b0[fj] = LDB(Bb, fj, 0);
        __builtin_amdgcn_s_setprio(1);
#pragma unroll
        for (int fi = 0; fi < 4; ++fi)
#pragma unroll
            for (int fj = 0; fj < 4; ++fj)
                acc[fi][fj] = __builtin_amdgcn_mfma_f32_16x16x32_bf16(
                    a0[fi], b0[fj], acc[fi][fj], 0, 0, 0);
        __builtin_amdgcn_s_setprio(0);

        // ks1: a-frags (their vmcnt wait retires the stage), B frags, MFMA
        bf16x8 a1[4], b1[4];
#pragma unroll
        for (int fi = 0; fi < 4; ++fi) a1[fi] = LDA(fb + 16 + fi);
#pragma unroll
        for (int fj = 0; fj < 4; ++fj) b1[fj] = LDB(Bb, fj, 1);
        __builtin_amdgcn_s_setprio(1);
#pragma unroll
        for (int fi = 0; fi < 4; ++fi)
#pragma unroll
            for (int fj = 0; fj < 4; ++fj)
                acc[fi][fj] = __builtin_amdgcn_mfma_f32_16x16x32_bf16(
                    a1[fi], b1[fj], acc[fi][fj], 0, 0, 0);
        __builtin_amdgcn_s_setprio(0);
    }
#undef GLD_B
#undef LDB
#undef LDA

    // Epilogue: D row=(lane>>4)*4+reg (within 16), col=l15; add bias, store f32.
    const int nbase = h * WW + wave_n + l15;
#pragma unroll
    for (int fi = 0; fi < 4; ++fi) {
        int mrow = m0 + wave_m + fi * 16 + lg * 4;
#pragma unroll
        for (int r = 0; r < 4; ++r) {
            float bv = bias[mrow + r];
#pragma unroll
            for (int fj = 0; fj < 4; ++fj)
                out[(size_t)(mrow + r) * (HH * WW) + nbase + fj * 16] = acc[fi][fj][r] + bv;
        }
    }
}

extern "C" void kernel_launch(void* const* d_in, const int* in_sizes, int n_in,
                              void* d_out, int out_size, void* d_ws, size_t ws_size,
                              hipStream_t stream) {
    (void)in_sizes; (void)n_in; (void)out_size; (void)ws_size;
    const float* x    = (const float*)d_in[0];   // 128*256*256
    const float* w    = (const float*)d_in[1];   // 256*128*3*3
    const float* bias = (const float*)d_in[2];   // 256
    float* out = (float*)d_out;

    unsigned short* xp  = (unsigned short*)d_ws;            // bf16 [258][258][128]
    unsigned short* apk = xp + XP_ELEMS;                    // bf16 fragment-packed weights

    prep<<<dim3(2241), dim3(256), 0, stream>>>(x, w, xp, apk);
    conv_mfma<<<dim3(512), dim3(512), 0, stream>>>(xp, apk, bias, out);
}

// Round 9
// 131.192 us; speedup vs baseline: 1.0764x; 1.0764x over previous
//
#include <hip/hip_runtime.h>
#include <hip/hip_bf16.h>
#include <stdint.h>

// Conv2d: x[128][256][256] (f32), w[256][128][3][3] (f32), bias[256] (f32)
// out[256][256][256] (f32).  pad=1, stride=1.
// bf16 MFMA implicit GEMM: M=COUT=256, N=65536 pixels, K=9 taps x 128 ch = 1152.
//   ws: x_p bf16 [258][258][128] (padded, channel-innermost), W_pk bf16 [9][256][128].
//
// R11 (post-mortem R10: A-from-global regressed -- L2 latency on the critical
// path + 4x A fetch + FIFO drain. Best = R7 44.1us. R7's per-tile 5880 cyc =
// MFMA 2483 + LDSrd 2304 + wr 512 SERIALIZED: each phase issues ds_reads and
// immediately waits. m201 (same geometry, ~3300 cyc/tile) hides read latency
// by issuing reads ONE PHASE AHEAD with counted lgkm waits -- m196 shows this
// fine interleave is worth 7-27%):
//   - R7 structure preserved exactly: 4 phases/tile, stage FIFO
//     {A0,A2,B0,B1,B2,B3,A1,A3}, vmcnt(2) after ph0 and ph3, raw s_barrier.
//   - NEW: register read-pipeline. ph1 also reads ph2's b1/a2; ph2 reads
//     ph3's a3. Compiler emits counted lgkmcnt automatically (C++ derefs, no
//     rule-18 asm hazard); sched_barrier(0) at region boundaries pins issue
//     order. RA1 stays after ph0's vmcnt(2) (its LDS data lands there) --
//     race-freedom identical to R7 by construction.
// FP accumulation order identical -> bit-identical output expected.

#define CIN   128
#define COUT  256
#define HH    256
#define WW    256
#define HP    258
#define WP    258
#define XP_ELEMS (HP * WP * CIN)   // 8,520,192 bf16 elements

typedef __attribute__((ext_vector_type(8))) __bf16 bf16x8;
typedef __attribute__((ext_vector_type(4))) float  floatx4;
typedef __attribute__((ext_vector_type(8))) short  short8;

#define AS1 __attribute__((address_space(1)))
#define AS3 __attribute__((address_space(3)))

// ---------------- fused prep: xpose_pad | wpack | zero_border ----------------
__global__ __launch_bounds__(256) void prep(const float* __restrict__ x,
                                            const float* __restrict__ w,
                                            unsigned short* __restrict__ xp,
                                            unsigned short* __restrict__ wpk) {
    __shared__ __align__(16) unsigned short tile[64][136];  // xpose region only
    const int bid = blockIdx.x;
    const int t   = threadIdx.x;
    if (bid < 1024) {
        // transpose+cast x[c][h][w] -> x_p[h+1][w+1][c]
        int h  = bid >> 2;
        int w0 = (bid & 3) << 6;
        int wl = t & 63, icq = t >> 6;
        const float* src = x + h * WW + w0 + wl;
#pragma unroll
        for (int icb = 0; icb < 32; ++icb) {
            int ic = icb * 4 + icq;
            __hip_bfloat16 b = __float2bfloat16(src[ic * (HH * WW)]);
            tile[wl][ic] = __builtin_bit_cast(unsigned short, b);
        }
        __syncthreads();
        int wl2 = t >> 2, q = t & 3;    // 64 rows x 4 chunks of 64B
        const short8* s8 = (const short8*)&tile[wl2][q * 32];
        short8* d8 = (short8*)(xp + ((size_t)(h + 1) * WP + (w0 + 1) + wl2) * CIN + q * 32);
#pragma unroll
        for (int i = 0; i < 4; ++i) d8[i] = s8[i];
    } else if (bid < 2176) {
        // pack weights -> bf16 W_pk[kk][o][ic]
        int idx = (bid - 1024) * 256 + t;           // 0..294911
        int kk  = idx >> 15;
        int rem = idx & 32767;                      // o*128 + ic
        __hip_bfloat16 b = __float2bfloat16(w[rem * 9 + kk]);
        wpk[idx] = __builtin_bit_cast(unsigned short, b);
    } else {
        // zero the padded border: 1028 px x 16 octets, short8 stores
        int cid = (bid - 2176) * 256 + t;           // 0..16447
        if (cid < 16448) {
            int p = cid >> 4, oct = cid & 15;
            int hp, wp;
            if (p < 258)      { hp = 0;   wp = p; }
            else if (p < 516) { hp = 257; wp = p - 258; }
            else { int s = p - 516; hp = 1 + (s >> 1); wp = (s & 1) * 257; }
            short8 z = {0, 0, 0, 0, 0, 0, 0, 0};
            *(short8*)(xp + ((size_t)hp * WP + wp) * CIN + oct * 8) = z;
        }
    }
}

// ---------------- main: 256(M) x 256(pixels of row h), 8 waves, 18 K-tiles x 4 phases ----------------
// Per buffer: A[256 o][64 ch] at 0, B[256 px][64 ch] at 16384 shorts.
// Swizzle: physical octet = logical octet ^ (row & 7)  (octet = 16 B).
__global__ __launch_bounds__(512, 2) void conv_mfma(
    const unsigned short* __restrict__ xp,   // [258][258][128] bf16
    const unsigned short* __restrict__ wpk,  // [9][256][128]   bf16
    const float* __restrict__ bias,          // [256] f32
    float* __restrict__ out) {               // [256][65536] f32
    __shared__ __align__(16) unsigned short x_lds[2 * 32768];   // 131,072 B

    const int tid  = threadIdx.x;            // 0..511
    const int lane = tid & 63;
    const int wv   = tid >> 6;               // 0..7
    const int l15  = lane & 15;
    const int lg   = lane >> 4;              // 0..3
    const int wave_m = (wv >> 2) << 7;       // 0 or 128
    const int wave_n = (wv & 3) << 6;        // 0,64,128,192

    // XCD swizzle (bijective, 256 % 8 == 0): XCD k gets rows [k*32, k*32+32).
    const int orig = blockIdx.x;
    const int h    = ((orig & 7) << 5) | (orig >> 3);

    // Staging per-thread source offset: row-group tid>>3, pre-swizzled octet.
    const int soff = (tid >> 3) * CIN + ((((tid & 7) ^ ((tid >> 3) & 7))) << 3);
    // Per-thread swizzled read octet (shorts); ks=1 flips bit2 (^32 shorts).
    const int aoct = (lg ^ (l15 & 7)) << 3;

#define GLD_A(nb_, src_, i_) \
    __builtin_amdgcn_global_load_lds((const AS1 void*)((src_) + (i_) * 8192), \
        (AS3 void*)((nb_) + (i_) * 4096 + tid * 8), 16, 0, 0)
#define GLD_B(nb_, src_, i_) \
    __builtin_amdgcn_global_load_lds((const AS1 void*)((src_) + (i_) * 8192), \
        (AS3 void*)((nb_) + 16384 + (i_) * 4096 + tid * 8), 16, 0, 0)
#define LDA(Ab_, mb_, kx_) \
    (*(const bf16x8*)((Ab_) + (((mb_) + l15) << 6) + (aoct ^ (kx_))))
#define LDB(Ab_, nb2_, kx_) \
    (*(const bf16x8*)((Ab_) + 16384 + (((nb2_) + l15) << 6) + (aoct ^ (kx_))))
#define SBAR()  __builtin_amdgcn_s_barrier()
#define SCHED() __builtin_amdgcn_sched_barrier(0)

    floatx4 acc[8][4];
#pragma unroll
    for (int fi = 0; fi < 8; ++fi)
#pragma unroll
        for (int fj = 0; fj < 4; ++fj) {
            floatx4 z = {0.f, 0.f, 0.f, 0.f};
            acc[fi][fj] = z;
        }

    // ---- prologue: stage tile 0 into buf 0 in FIFO order {A0,A2,B0..B3,A1,A3} ----
    {
        const unsigned short* a0  = wpk + soff;                          // kk=0, hf=0
        const unsigned short* b0s = xp + ((size_t)h * WP) * CIN + soff;  // kh=0, kw=0
        unsigned short* nb = x_lds;
        GLD_A(nb, a0, 0); GLD_A(nb, a0, 2);
        GLD_B(nb, b0s, 0); GLD_B(nb, b0s, 1); GLD_B(nb, b0s, 2); GLD_B(nb, b0s, 3);
        GLD_A(nb, a0, 1); GLD_A(nb, a0, 3);
    }
    asm volatile("s_waitcnt vmcnt(2)" ::: "memory");   // first 6 (phase-0 data) landed
    SBAR(); SCHED();

#pragma unroll
    for (int t2 = 0; t2 < 18; ++t2) {        // K-tile = (kk, ch-half)
        const int cur = t2 & 1;
        const unsigned short* Ab = x_lds + cur * 32768;
        unsigned short* nb = x_lds + (cur ^ 1) * 32768;
        const bool hn = (t2 < 17);
        const int tn  = t2 + 1;
        const int kkn = tn >> 1, hfn = tn & 1;
        const int khn = kkn / 3, kwn = kkn - khn * 3;
        const unsigned short* asrcn = wpk + (size_t)kkn * (COUT * CIN) + hfn * 64 + soff;
        const unsigned short* bsrcn = xp + ((size_t)(h + khn) * WP + kwn) * CIN + hfn * 64 + soff;

        bf16x8 b0[4], b1[4], a0[4], a1[4], a2[4], a3[4];

        // ===== phase 0: (m-half 0, ks 0) — reads for THIS phase (tile edge) =====
#pragma unroll
        for (int fj = 0; fj < 4; ++fj) b0[fj] = LDB(Ab, wave_n + fj * 16, 0);
#pragma unroll
        for (int i = 0; i < 4; ++i)    a0[i] = LDA(Ab, wave_m + i * 16, 0);
        if (hn) { GLD_A(nb, asrcn, 0); GLD_A(nb, asrcn, 2); }
        SBAR(); SCHED();
        __builtin_amdgcn_s_setprio(1);
#pragma unroll
        for (int i = 0; i < 4; ++i)
#pragma unroll
            for (int fj = 0; fj < 4; ++fj)
                acc[i][fj] = __builtin_amdgcn_mfma_f32_16x16x32_bf16(a0[i], b0[fj], acc[i][fj], 0, 0, 0);
        __builtin_amdgcn_s_setprio(0);
        SCHED();
        if (hn) asm volatile("s_waitcnt vmcnt(2)" ::: "memory");  // this tile's A1,A3 landed
        else    asm volatile("s_waitcnt vmcnt(0)" ::: "memory");
        SBAR(); SCHED();

        // ===== phase 1: (m-half 1, ks 0) — also prefetch ph2's b1,a2 =====
#pragma unroll
        for (int i = 0; i < 4; ++i)    a1[i] = LDA(Ab, wave_m + 64 + i * 16, 0);
#pragma unroll
        for (int fj = 0; fj < 4; ++fj) b1[fj] = LDB(Ab, wave_n + fj * 16, 32);
#pragma unroll
        for (int i = 0; i < 4; ++i)    a2[i] = LDA(Ab, wave_m + i * 16, 32);
        if (hn) { GLD_B(nb, bsrcn, 0); GLD_B(nb, bsrcn, 1); }
        SBAR(); SCHED();
        __builtin_amdgcn_s_setprio(1);
#pragma unroll
        for (int i = 0; i < 4; ++i)
#pragma unroll
            for (int fj = 0; fj < 4; ++fj)
                acc[4 + i][fj] = __builtin_amdgcn_mfma_f32_16x16x32_bf16(a1[i], b0[fj], acc[4 + i][fj], 0, 0, 0);
        __builtin_amdgcn_s_setprio(0);
        SCHED();
        SBAR(); SCHED();

        // ===== phase 2: (m-half 0, ks 1) — also prefetch ph3's a3 =====
#pragma unroll
        for (int i = 0; i < 4; ++i)    a3[i] = LDA(Ab, wave_m + 64 + i * 16, 32);
        if (hn) { GLD_B(nb, bsrcn, 2); GLD_B(nb, bsrcn, 3); }
        SBAR(); SCHED();
        __builtin_amdgcn_s_setprio(1);
#pragma unroll
        for (int i = 0; i < 4; ++i)
#pragma unroll
            for (int fj = 0; fj < 4; ++fj)
                acc[i][fj] = __builtin_amdgcn_mfma_f32_16x16x32_bf16(a2[i], b1[fj], acc[i][fj], 0, 0, 0);
        __builtin_amdgcn_s_setprio(0);
        SCHED();
        SBAR(); SCHED();

        // ===== phase 3: (m-half 1, ks 1) =====
        if (hn) { GLD_A(nb, asrcn, 1); GLD_A(nb, asrcn, 3); }
        SBAR(); SCHED();
        __builtin_amdgcn_s_setprio(1);
#pragma unroll
        for (int i = 0; i < 4; ++i)
#pragma unroll
            for (int fj = 0; fj < 4; ++fj)
                acc[4 + i][fj] = __builtin_amdgcn_mfma_f32_16x16x32_bf16(a3[i], b1[fj], acc[4 + i][fj], 0, 0, 0);
        __builtin_amdgcn_s_setprio(0);
        SCHED();
        if (hn) asm volatile("s_waitcnt vmcnt(2)" ::: "memory");  // next tile's first 6 landed
        SBAR(); SCHED();
    }
#undef GLD_A
#undef GLD_B
#undef LDA
#undef LDB
#undef SBAR
#undef SCHED

    // Epilogue: D row=(lane>>4)*4+reg (within 16), col=l15; add bias, store f32.
    const int nbase = h * WW + wave_n + l15;
#pragma unroll
    for (int fi = 0; fi < 8; ++fi) {
        int mrow = wave_m + fi * 16 + lg * 4;
#pragma unroll
        for (int r = 0; r < 4; ++r) {
            float bv = bias[mrow + r];
#pragma unroll
            for (int fj = 0; fj < 4; ++fj)
                out[(size_t)(mrow + r) * (HH * WW) + nbase + fj * 16] = acc[fi][fj][r] + bv;
        }
    }
}

extern "C" void kernel_launch(void* const* d_in, const int* in_sizes, int n_in,
                              void* d_out, int out_size, void* d_ws, size_t ws_size,
                              hipStream_t stream) {
    (void)in_sizes; (void)n_in; (void)out_size; (void)ws_size;
    const float* x    = (const float*)d_in[0];   // 128*256*256
    const float* w    = (const float*)d_in[1];   // 256*128*3*3
    const float* bias = (const float*)d_in[2];   // 256
    float* out = (float*)d_out;

    unsigned short* xp  = (unsigned short*)d_ws;            // bf16 [258][258][128]
    unsigned short* wpk = xp + XP_ELEMS;                    // bf16 [9][256][128]

    prep<<<dim3(2241), dim3(256), 0, stream>>>(x, w, xp, wpk);
    conv_mfma<<<dim3(256), dim3(512), 0, stream>>>(xp, wpk, bias, out);
}